// Round 11
// baseline (485.185 us; speedup 1.0000x reference)
//
#include <hip/hip_runtime.h>
#include <hip/hip_bf16.h>

// Few-shot matching-network head + Conv4 backbone (MI355X, gfx950). Round 11.
//
// R10: 456 us; conv2 (convm64) 55us x2 with Occupancy 26% - GRID-limited
// (400 imgs x 7 wave-tiles = 2800 waves vs 8192 slots); HBM 2.2 TB/s because
// ~2 waves/SIMD can't hide load latency. Fixes:
//  - cout-split conv kernels (blockIdx.y in {0,1}, 32 couts/wave): 2x waves
//    (conv2 -> 5600 waves ~68% occ; conv3 32col x 32cout -> 3200 waves).
//  - explicit B-prefetch software pipeline (k-step kk+1 loads issued during
//    kk's MFMAs); acc drops to 32 VGPR.
// Layout / weights / head / chunking proven r8-r10 (absmax 0.0039).

#define BB 8
#define SS 25
#define TT 75
#define CC 5
#define DD 2304
#define NSUP 200
#define NTGT 600
#define NTOT 800
#define EPSF 1e-8f

typedef __attribute__((ext_vector_type(8))) short bf16x8;
typedef __attribute__((ext_vector_type(4))) float f32x4;

__device__ __forceinline__ float load_ext(const void* p, size_t idx, int isf32) {
  if (isf32) return ((const float*)p)[idx];
  unsigned short u = ((const unsigned short*)p)[idx];
  union { unsigned int i; float f; } v;
  v.i = ((unsigned int)u) << 16;
  return v.f;
}

// ---- dtype probe (proven r3-r10): flag=1 => external data is fp32 ----
__global__ void fsc_probe_dtype_k(const unsigned short* __restrict__ w2raw,
                                  int nelems, int* __restrict__ flag) {
  __shared__ int cnt;
  if (threadIdx.x == 0) cnt = 0;
  __syncthreads();
  int local = 0;
  for (int i = threadIdx.x; i < nelems; i += 256) {
    unsigned short u = w2raw[i];
    int ex = (u >> 7) & 0xFF;
    if (ex != 0 && (ex < 0x69 || ex > 0x84)) local++;
  }
  atomicAdd(&cnt, local);
  __syncthreads();
  if (threadIdx.x == 0) *flag = (cnt > nelems / 8) ? 1 : 0;
}

// ---- conv1 NHWC4 weight repack: [s=2][t=4][lane=64][j=8] bf16 (proven r10) ----
__global__ void fsc_repack_w1m_k(const void* __restrict__ W,
                                 __hip_bfloat16* __restrict__ Wf,
                                 const int* __restrict__ flag) {
  const int isf32 = *flag;
  int i = blockIdx.x * blockDim.x + threadIdx.x;
  if (i >= 4096) return;
  int j = i & 7;
  int lane = (i >> 3) & 63;
  int t = (i >> 9) & 3;
  int s = i >> 11;
  int kk = (lane >> 4) * 8 + j;
  int co = t * 16 + (lane & 15);
  float v = 0.f;
  int kh, kwp, ci;
  bool live = false;
  if (s == 0) { kh = kk >> 4; kwp = (kk & 15) >> 2; ci = kk & 3; live = true; }
  else if (kk < 16) { kh = 2; kwp = kk >> 2; ci = kk & 3; live = true; }
  if (live && kwp < 3 && ci < 3)
    v = load_ext(W, (size_t)((co * 3 + ci) * 3 + kh) * 3 + kwp, isf32);
  Wf[i] = __float2bfloat16(v);
}

// ---- conv2/3/4 weight repack: OIHW [64][64][3][3] -> bf16 A-frag order ----
__global__ void fsc_repack_wm_k(const void* __restrict__ W,
                                __hip_bfloat16* __restrict__ Wf,
                                const int* __restrict__ flag) {
  const int isf32 = *flag;
  int o = blockIdx.x * blockDim.x + threadIdx.x;
  if (o >= 36864) return;
  int j = o & 7;
  int lane = (o >> 3) & 63;
  int t = (o >> 9) & 3;
  int kk = o >> 11;       // 0..17
  int s = kk & 1;
  int khw = kk >> 1;      // kh*3+kw
  int kh = khw / 3, kw = khw - kh * 3;
  int co = t * 16 + (lane & 15);
  int ci = s * 32 + (lane >> 4) * 8 + j;
  float v = load_ext(W, (size_t)((co * 64 + ci) * 3 + kh) * 3 + kw, isf32);
  Wf[o] = __float2bfloat16(v);
}

// ---- zero the 1-px border of an NHWC-padded [N][P][P][64] bf16 buffer ----
template <int P>
__global__ void fsc_zero_border_k(__hip_bfloat16* __restrict__ buf, int N) {
  int i = blockIdx.x * blockDim.x + threadIdx.x;
  const int RP = 4 * P - 4;
  if (i >= N * RP * 64) return;
  int c = i & 63;
  int r = (i >> 6) % RP;
  int n = (i >> 6) / RP;
  int row, colp;
  if (r < P) { row = 0; colp = r; }
  else if (r < 2 * P) { row = P - 1; colp = r - P; }
  else if (r < 3 * P - 2) { row = r - 2 * P + 1; colp = 0; }
  else { row = r - (3 * P - 2) + 1; colp = P - 1; }
  buf[(((size_t)n * P + row) * P + colp) * 64 + c] = __float2bfloat16(0.f);
}

// ---- zero X's pad cells: rows 84..85 (all w) + cols 84..85 (h<84), 4 ch ----
__global__ void fsc_zero_xb_k(__hip_bfloat16* __restrict__ X, int N) {
  int i = blockIdx.x * blockDim.x + threadIdx.x;
  if (i >= N * 1360) return;  // (2*86 + 84*2) * 4
  int c = i & 3;
  int p = (i >> 2) % 340;
  int n = (i >> 2) / 340;
  int h, w;
  if (p < 172) { h = 84 + (p / 86); w = p % 86; }
  else { int pp = p - 172; h = pp >> 1; w = 84 + (pp & 1); }
  X[(((size_t)n * 86 + h) * 86 + w) * 4 + c] = __float2bfloat16(0.f);
}

// ---- input transform: ext [img][3][84][84] -> bf16 NHWC4 [img][86][86][4] ----
__global__ void fsc_xform1_k(const void* __restrict__ x, int srcImg0,
                             __hip_bfloat16* __restrict__ X, int dstImg0,
                             int n, const int* __restrict__ flag) {
  const int isf32 = *flag;
  int i = blockIdx.x * blockDim.x + threadIdx.x;
  const int imgL = i / 7056;
  if (imgL >= n) return;
  const int sp = i - imgL * 7056;
  const int h = sp / 84, w = sp - h * 84;
  const size_t base = (size_t)(srcImg0 + imgL) * 21168;
  union { unsigned short u[4]; uint2 q; } pk;
#pragma unroll
  for (int ci = 0; ci < 3; ++ci)
    pk.u[ci] = __bfloat16_as_ushort(__float2bfloat16(load_ext(x, base + ci * 7056 + sp, isf32)));
  pk.u[3] = 0;
  *(uint2*)(void*)(X + (((size_t)(dstImg0 + imgL) * 86 + h) * 86 + w) * 4) = pk.q;
}

// ---- conv1 MFMA, cout-split: 64 cols x 32 couts/wave, 2 k-steps, prefetched ----
__global__ void fsc_conv1s_k(const __hip_bfloat16* __restrict__ X,
                             const __hip_bfloat16* __restrict__ Wf,
                             const void* __restrict__ bias,
                             __hip_bfloat16* __restrict__ out, int N,
                             const int* __restrict__ flag) {
  constexpr int TPI = 28;  // ceil(1764/64)
  const int wid = blockIdx.x * 4 + (threadIdx.x >> 6);
  const int img = wid / TPI;
  if (img >= N) return;
  const int tl = wid - img * TPI;
  const int g = blockIdx.y;  // cout half
  const int lane = threadIdx.x & 63;
  const int nidx = lane & 15, quad = lane >> 4;

  int col[4];
  bool val[4];
  int hoA[4], woA[4];
#pragma unroll
  for (int p = 0; p < 4; ++p) {
    col[p] = tl * 64 + p * 16 + nidx;
    val[p] = col[p] < 1764;
    if (!val[p]) col[p] = 1763;
    hoA[p] = col[p] / 42;
    woA[p] = col[p] - hoA[p] * 42;
  }

  f32x4 acc[4][2];
#pragma unroll
  for (int p = 0; p < 4; ++p)
#pragma unroll
    for (int tt = 0; tt < 2; ++tt) acc[p][tt] = (f32x4){0.f, 0.f, 0.f, 0.f};

  bf16x8 bcur[4], bnxt[4];
#pragma unroll
  for (int p = 0; p < 4; ++p) {
    const int hi = 2 * hoA[p] + (quad >> 1);
    bcur[p] = *(const bf16x8*)(const void*)(
        X + (((size_t)img * 86 + hi) * 86 + 2 * woA[p]) * 4 + (quad & 1) * 8);
  }
#pragma unroll
  for (int s = 0; s < 2; ++s) {
    if (s == 0) {
#pragma unroll
      for (int p = 0; p < 4; ++p) {
        const int hi = 2 * hoA[p] + 2;
        bnxt[p] = *(const bf16x8*)(const void*)(
            X + (((size_t)img * 86 + hi) * 86 + 2 * woA[p]) * 4 + (quad & 1) * 8);
      }
    }
#pragma unroll
    for (int tt = 0; tt < 2; ++tt) {
      bf16x8 a = *(const bf16x8*)(const void*)(
          Wf + ((size_t)(s * 4 + g * 2 + tt) * 64 + lane) * 8);
#pragma unroll
      for (int p = 0; p < 4; ++p)
        acc[p][tt] = __builtin_amdgcn_mfma_f32_16x16x32_bf16(a, bcur[p], acc[p][tt], 0, 0, 0);
    }
    if (s == 0) {
#pragma unroll
      for (int p = 0; p < 4; ++p) bcur[p] = bnxt[p];
    }
  }

  const int isf32 = *flag;
#pragma unroll
  for (int p = 0; p < 4; ++p) {
#pragma unroll
    for (int tt = 0; tt < 2; ++tt) {
      float v[4];
#pragma unroll
      for (int r = 0; r < 4; ++r) {
        const int cout = (g * 2 + tt) * 16 + quad * 4 + r;
        float xv = acc[p][tt][r] + load_ext(bias, cout, isf32);
        v[r] = xv > 0.f ? xv : 0.f;
      }
      if (val[p]) {
        __hip_bfloat16* o = out + (((size_t)img * 44 + (hoA[p] + 1)) * 44 +
                                   (woA[p] + 1)) * 64 + (g * 2 + tt) * 16 + quad * 4;
        union { unsigned short u[4]; uint2 w; } pk;
#pragma unroll
        for (int r = 0; r < 4; ++r) pk.u[r] = __bfloat16_as_ushort(__float2bfloat16(v[r]));
        *(uint2*)(void*)o = pk.w;
      }
    }
  }
}

// ---- cout-split implicit-GEMM conv: CG*16 cols x 32 couts/wave, B prefetch ----
template <int HO, int PWI, int PWO, int ROFF, int CG>
__global__ void fsc_convs_k(const __hip_bfloat16* __restrict__ in,
                            const __hip_bfloat16* __restrict__ Wf,
                            const void* __restrict__ bias,
                            __hip_bfloat16* __restrict__ out, int N,
                            const int* __restrict__ flag) {
  constexpr int COLS = CG * 16;
  constexpr int TPI = (HO * HO + COLS - 1) / COLS;
  const int wid = blockIdx.x * 4 + (threadIdx.x >> 6);
  const int img = wid / TPI;
  if (img >= N) return;
  const int tl = wid - img * TPI;
  const int g = blockIdx.y;  // cout half
  const int lane = threadIdx.x & 63;
  const int nidx = lane & 15, quad = lane >> 4;

  int col[CG];
  bool val[CG];
  int hoA[CG], woA[CG];
  const __hip_bfloat16* bsrc[CG];
#pragma unroll
  for (int p = 0; p < CG; ++p) {
    col[p] = tl * COLS + p * 16 + nidx;
    val[p] = col[p] < HO * HO;
    if (!val[p]) col[p] = HO * HO - 1;
    hoA[p] = col[p] / HO;
    woA[p] = col[p] - hoA[p] * HO;
    bsrc[p] = in + (((size_t)img * PWI + (2 * hoA[p] + ROFF)) * PWI +
                    (2 * woA[p] + ROFF)) * 64 + quad * 8;
  }
  const __hip_bfloat16* asrc = Wf + lane * 8;

  f32x4 acc[CG][2];
#pragma unroll
  for (int p = 0; p < CG; ++p)
#pragma unroll
    for (int tt = 0; tt < 2; ++tt) acc[p][tt] = (f32x4){0.f, 0.f, 0.f, 0.f};

  bf16x8 bcur[CG];
#pragma unroll
  for (int p = 0; p < CG; ++p) bcur[p] = *(const bf16x8*)(const void*)bsrc[p];

#pragma unroll
  for (int kk = 0; kk < 18; ++kk) {
    bf16x8 bnxt[CG];
    if (kk < 17) {
      const int k2 = kk + 1;
      const int s2 = k2 & 1;
      const int khw2 = k2 >> 1;
      const int kh2 = khw2 / 3, kw2 = khw2 - kh2 * 3;
      const int bo = (kh2 * PWI + kw2) * 64 + s2 * 32;
#pragma unroll
      for (int p = 0; p < CG; ++p) bnxt[p] = *(const bf16x8*)(const void*)(bsrc[p] + bo);
    }
#pragma unroll
    for (int tt = 0; tt < 2; ++tt) {
      bf16x8 a = *(const bf16x8*)(const void*)(asrc + (kk * 4 + g * 2 + tt) * 512);
#pragma unroll
      for (int p = 0; p < CG; ++p)
        acc[p][tt] = __builtin_amdgcn_mfma_f32_16x16x32_bf16(a, bcur[p], acc[p][tt], 0, 0, 0);
    }
    if (kk < 17) {
#pragma unroll
      for (int p = 0; p < CG; ++p) bcur[p] = bnxt[p];
    }
  }

  const int isf32 = *flag;
#pragma unroll
  for (int p = 0; p < CG; ++p) {
#pragma unroll
    for (int tt = 0; tt < 2; ++tt) {
      float v[4];
#pragma unroll
      for (int r = 0; r < 4; ++r) {
        const int cout = (g * 2 + tt) * 16 + quad * 4 + r;
        float xv = acc[p][tt][r] + load_ext(bias, cout, isf32);
        v[r] = xv > 0.f ? xv : 0.f;
      }
      if (val[p]) {
        __hip_bfloat16* o = out + (((size_t)img * PWO + (hoA[p] + 1)) * PWO +
                                   (woA[p] + 1)) * 64 + (g * 2 + tt) * 16 + quad * 4;
        union { unsigned short u[4]; uint2 w; } pk;
#pragma unroll
        for (int r = 0; r < 4; ++r) pk.u[r] = __bfloat16_as_ushort(__float2bfloat16(v[r]));
        *(uint2*)(void*)o = pk.w;
      }
    }
  }
}

// ---- 32-col MFMA conv, EMB output (conv4; proven r6-r10) ----
__global__ void fsc_conv4_k(const __hip_bfloat16* __restrict__ in,
                            const __hip_bfloat16* __restrict__ Wf,
                            const void* __restrict__ bias, float* __restrict__ emb,
                            int N, const int* __restrict__ flag) {
  constexpr int HO = 6, PWI = 13;
  constexpr int TPI = 2;  // ceil(36/32)
  const int wid = blockIdx.x * 4 + (threadIdx.x >> 6);
  const int img = wid / TPI;
  if (img >= N) return;
  const int tl = wid - img * TPI;
  const int lane = threadIdx.x & 63;
  const int nidx = lane & 15, quad = lane >> 4;

  int col0 = tl * 32 + nidx;
  int col1 = col0 + 16;
  const bool val0 = col0 < HO * HO;
  const bool val1 = col1 < HO * HO;
  if (!val0) col0 = HO * HO - 1;
  if (!val1) col1 = HO * HO - 1;
  const int ho0 = col0 / HO, wo0 = col0 - ho0 * HO;
  const int ho1 = col1 / HO, wo1 = col1 - ho1 * HO;

  const __hip_bfloat16* bsrc0 =
      in + (((size_t)img * PWI + 2 * ho0) * PWI + 2 * wo0) * 64 + quad * 8;
  const __hip_bfloat16* bsrc1 =
      in + (((size_t)img * PWI + 2 * ho1) * PWI + 2 * wo1) * 64 + quad * 8;
  const __hip_bfloat16* asrc = Wf + lane * 8;

  f32x4 acc[2][4];
#pragma unroll
  for (int p = 0; p < 2; ++p)
#pragma unroll
    for (int t = 0; t < 4; ++t) acc[p][t] = (f32x4){0.f, 0.f, 0.f, 0.f};

#pragma unroll
  for (int kk = 0; kk < 18; ++kk) {
    const int s = kk & 1;
    const int khw = kk >> 1;
    const int kh = khw / 3, kw = khw - kh * 3;
    const int boff = (kh * PWI + kw) * 64 + s * 32;
    bf16x8 b0 = *(const bf16x8*)(const void*)(bsrc0 + boff);
    bf16x8 b1 = *(const bf16x8*)(const void*)(bsrc1 + boff);
#pragma unroll
    for (int t = 0; t < 4; ++t) {
      bf16x8 a = *(const bf16x8*)(const void*)(asrc + (kk * 4 + t) * 512);
      acc[0][t] = __builtin_amdgcn_mfma_f32_16x16x32_bf16(a, b0, acc[0][t], 0, 0, 0);
      acc[1][t] = __builtin_amdgcn_mfma_f32_16x16x32_bf16(a, b1, acc[1][t], 0, 0, 0);
    }
  }

  const int isf32 = *flag;
#pragma unroll
  for (int p = 0; p < 2; ++p) {
    const bool valid = p == 0 ? val0 : val1;
    const int col = p == 0 ? col0 : col1;
#pragma unroll
    for (int t = 0; t < 4; ++t) {
      float v[4];
#pragma unroll
      for (int r = 0; r < 4; ++r) {
        const int cout = t * 16 + quad * 4 + r;
        float xv = acc[p][t][r] + load_ext(bias, cout, isf32);
        v[r] = xv > 0.f ? xv : 0.f;
      }
      if (valid) {
        float* o = emb + ((size_t)img * 36 + col) * 64 + t * 16 + quad * 4;
        *(f32x4*)(void*)o = (f32x4){v[0], v[1], v[2], v[3]};
      }
    }
  }
}

// ---- head (proven r3-r10) ----
__global__ void fsc_proto_k(const float* __restrict__ emb_s, const int* __restrict__ y,
                            float* __restrict__ protos) {
  int i = blockIdx.x * blockDim.x + threadIdx.x;
  if (i >= BB * CC * DD) return;
  int d = i % DD;
  int bc = i / DD;
  int c = bc % CC;
  int b = bc / CC;
  float sum = 0.f;
  for (int s = 0; s < SS; ++s) {
    if (y[b * SS + s] % CC == c) sum += emb_s[(size_t)(b * SS + s) * DD + d];
  }
  protos[i] = sum * 0.2f;
}

__global__ void fsc_pnorm_k(const float* __restrict__ protos, float* __restrict__ pn) {
  __shared__ float red[4];
  __shared__ float inv;
  const int bc = blockIdx.x;
  const float* p = protos + (size_t)bc * DD;
  float ss = 0.f;
  for (int d = threadIdx.x; d < DD; d += 256) { float v = p[d]; ss += v * v; }
#pragma unroll
  for (int off = 32; off > 0; off >>= 1) ss += __shfl_down(ss, off);
  if ((threadIdx.x & 63) == 0) red[threadIdx.x >> 6] = ss;
  __syncthreads();
  if (threadIdx.x == 0) {
    float nrm = sqrtf(red[0] + red[1] + red[2] + red[3]);
    nrm = nrm > EPSF ? nrm : EPSF;
    inv = 1.f / nrm;
  }
  __syncthreads();
  float sc = inv;
  for (int d = threadIdx.x; d < DD; d += 256) pn[(size_t)bc * DD + d] = p[d] * sc;
}

__global__ void fsc_preds_k(const float* __restrict__ emb_t, const float* __restrict__ pn,
                            void* __restrict__ out, const int* __restrict__ flag) {
  __shared__ float red[4][6];
  __shared__ float fin[6];
  const int isf32 = *flag;
  const int bt = blockIdx.x;
  const int b = bt / TT;
  const float* et = emb_t + (size_t)bt * DD;
  float e[9];
#pragma unroll
  for (int k = 0; k < 9; ++k) e[k] = et[threadIdx.x + 256 * k];
  float vals[6];
  {
    float ss = 0.f;
#pragma unroll
    for (int k = 0; k < 9; ++k) ss += e[k] * e[k];
    vals[0] = ss;
  }
  const float* pb = pn + (size_t)b * CC * DD;
#pragma unroll
  for (int c = 0; c < CC; ++c) {
    float s = 0.f;
#pragma unroll
    for (int k = 0; k < 9; ++k) s += e[k] * pb[(size_t)c * DD + threadIdx.x + 256 * k];
    vals[1 + c] = s;
  }
#pragma unroll
  for (int v = 0; v < 6; ++v) {
#pragma unroll
    for (int off = 32; off > 0; off >>= 1) vals[v] += __shfl_down(vals[v], off);
  }
  if ((threadIdx.x & 63) == 0) {
#pragma unroll
    for (int v = 0; v < 6; ++v) red[threadIdx.x >> 6][v] = vals[v];
  }
  __syncthreads();
  if (threadIdx.x < 6)
    fin[threadIdx.x] = red[0][threadIdx.x] + red[1][threadIdx.x] +
                       red[2][threadIdx.x] + red[3][threadIdx.x];
  __syncthreads();
  if (threadIdx.x < CC) {
    float nt = sqrtf(fin[0]);
    nt = nt > EPSF ? nt : EPSF;
    float r = fin[1 + threadIdx.x] / nt;
    if (isf32) ((float*)out)[(size_t)bt * CC + threadIdx.x] = r;
    else ((__hip_bfloat16*)out)[(size_t)bt * CC + threadIdx.x] = __float2bfloat16(r);
  }
}

static inline int fsc_cdiv(int a, int b) { return (a + b - 1) / b; }
static inline int imin(int a, int b) { return a < b ? a : b; }
static inline int imax(int a, int b) { return a > b ? a : b; }

extern "C" void kernel_launch(void* const* d_in, const int* in_sizes, int n_in,
                              void* d_out, int out_size, void* d_ws, size_t ws_size,
                              hipStream_t stream) {
  const void* xs = d_in[0];
  const void* xt = d_in[1];
  const int* y = (const int*)d_in[2];
  const void* W1 = d_in[3];
  const void* b1 = d_in[4];
  const void* W2 = d_in[5];
  const void* b2 = d_in[6];
  const void* W3 = d_in[7];
  const void* b3 = d_in[8];
  const void* W4 = d_in[9];
  const void* b4 = d_in[10];

  // ---- workspace layout: fixed ~25.6 MB + X/A1/A2 chunk buffers ----
  char* w = (char*)d_ws;
  int* flag = (int*)w;                      w += 256;
  __hip_bfloat16* Wf1 = (__hip_bfloat16*)w; w += 4096 * 2;
  __hip_bfloat16* Wf2 = (__hip_bfloat16*)w; w += 36864 * 2;
  __hip_bfloat16* Wf3 = (__hip_bfloat16*)w; w += 36864 * 2;
  __hip_bfloat16* Wf4 = (__hip_bfloat16*)w; w += 36864 * 2;
  float* protos = (float*)w;                w += (size_t)BB * CC * DD * 4;
  float* pn = (float*)w;                    w += (size_t)BB * CC * DD * 4;
  float* emb = (float*)w;                   w += (size_t)NTOT * DD * 4;           // 7.37 MB
  __hip_bfloat16* C3 = (__hip_bfloat16*)w;  w += (size_t)NTOT * 13 * 13 * 64 * 2; // 17.3 MB
  char* chunk0 = w;
  const size_t fixedB = (size_t)(w - (char*)d_ws);
  const size_t szX  = (size_t)86 * 86 * 4 * 2;    //  59,168 B/img
  const size_t szA1 = (size_t)44 * 44 * 64 * 2;   // 247,808 B/img
  const size_t szA2 = (size_t)23 * 23 * 64 * 2;   //  67,712 B/img
  const size_t perImgB = szX + szA1 + szA2;        // 374,688 B/img

  int CH = 50;
  const int cands[5] = {400, 200, 100, 67, 50};
  for (int k = 0; k < 5; ++k) {
    if (fixedB + (size_t)cands[k] * perImgB <= ws_size) { CH = cands[k]; break; }
  }
  __hip_bfloat16* X  = (__hip_bfloat16*)chunk0;
  __hip_bfloat16* A1 = (__hip_bfloat16*)(chunk0 + (size_t)CH * szX);
  __hip_bfloat16* A2 = (__hip_bfloat16*)(chunk0 + (size_t)CH * (szX + szA1));

  // 1. dtype probe + weight repacks
  fsc_probe_dtype_k<<<1, 256, 0, stream>>>((const unsigned short*)W2, 64 * 64 * 9, flag);
  fsc_repack_w1m_k<<<fsc_cdiv(4096, 256), 256, 0, stream>>>(W1, Wf1, flag);
  fsc_repack_wm_k<<<fsc_cdiv(36864, 256), 256, 0, stream>>>(W2, Wf2, flag);
  fsc_repack_wm_k<<<fsc_cdiv(36864, 256), 256, 0, stream>>>(W3, Wf3, flag);
  fsc_repack_wm_k<<<fsc_cdiv(36864, 256), 256, 0, stream>>>(W4, Wf4, flag);

  // 2. zero pad cells (interiors rewritten each chunk; pads stay 0)
  fsc_zero_xb_k<<<fsc_cdiv(CH * 1360, 256), 256, 0, stream>>>(X, CH);
  fsc_zero_border_k<44><<<fsc_cdiv(CH * (4 * 44 - 4) * 64, 256), 256, 0, stream>>>(A1, CH);
  fsc_zero_border_k<23><<<fsc_cdiv(CH * (4 * 23 - 4) * 64, 256), 256, 0, stream>>>(A2, CH);
  fsc_zero_border_k<13><<<fsc_cdiv(NTOT * (4 * 13 - 4) * 64, 256), 256, 0, stream>>>(C3, NTOT);

  // 3. chunks over GLOBAL image index (support 0..199, target 200..799)
  for (int g0 = 0; g0 < NTOT; g0 += CH) {
    const int n = imin(CH, NTOT - g0);
    if (g0 < NSUP) {
      const int cnt = imin(g0 + n, NSUP) - g0;
      fsc_xform1_k<<<fsc_cdiv(cnt * 7056, 256), 256, 0, stream>>>(
          xs, g0, X, 0, cnt, flag);
    }
    if (g0 + n > NSUP) {
      const int tStart = imax(g0, NSUP);
      const int cnt = g0 + n - tStart;
      fsc_xform1_k<<<fsc_cdiv(cnt * 7056, 256), 256, 0, stream>>>(
          xt, tStart - NSUP, X, tStart - g0, cnt, flag);
    }
    // conv1: NHWC4 -> 42x42 into 44-pad; TPI=28, cout-split
    fsc_conv1s_k<<<dim3(fsc_cdiv(n * 28, 4), 2), 256, 0, stream>>>(
        X, Wf1, b1, A1, n, flag);
    // conv2: 44-pad -> 21x21 into 23-pad; ROFF=1; 64 cols, cout-split (TPI=7)
    fsc_convs_k<21, 44, 23, 1, 4><<<dim3(fsc_cdiv(n * 7, 4), 2), 256, 0, stream>>>(
        A1, Wf2, b2, A2, n, flag);
    // conv3: 23-pad -> 11x11 into 13-pad; ROFF=0; 32 cols, cout-split (TPI=4)
    fsc_convs_k<11, 23, 13, 0, 2><<<dim3(fsc_cdiv(n * 4, 4), 2), 256, 0, stream>>>(
        A2, Wf3, b3, C3 + (size_t)g0 * 13 * 13 * 64, n, flag);
  }

  // 4. conv4 full batch: 13-pad -> fp32 emb [800][2304]
  fsc_conv4_k<<<fsc_cdiv(NTOT * 2, 4), 256, 0, stream>>>(C3, Wf4, b4, emb, NTOT, flag);

  // 5. head
  fsc_proto_k<<<fsc_cdiv(BB * CC * DD, 256), 256, 0, stream>>>(emb, y, protos);
  fsc_pnorm_k<<<BB * CC, 256, 0, stream>>>(protos, pn);
  fsc_preds_k<<<NTGT, 256, 0, stream>>>(emb + (size_t)NSUP * DD, pn, d_out, flag);
}

// Round 12
// 445.894 us; speedup vs baseline: 1.0881x; 1.0881x over previous
//
#include <hip/hip_runtime.h>
#include <hip/hip_bf16.h>

// Few-shot matching-network head + Conv4 backbone (MI355X, gfx950). Round 12.
//
// R11: 485 us REGRESSION. cout-split doubled conv2 FETCH 98->184 MB (L2 does
// not dedupe across y-blocks) - lesson: only add waves along DISJOINT-traffic
// dimensions (columns). This round (revert split +):
//  - CH=640/600 (ws is 256 MiB; r10 used 175 MB): conv2 main dispatch ~9k waves.
//  - column-split: conv2 32col x 64cout (TPI=14), conv3 16col (TPI=8).
//  - depth-4 rotating B-prefetch: kk+3's loads issued before kk's MFMAs.
// conv1m / conv4 / head / layout proven r10 (456 us, absmax 0.0039).

#define BB 8
#define SS 25
#define TT 75
#define CC 5
#define DD 2304
#define NSUP 200
#define NTGT 600
#define NTOT 800
#define EPSF 1e-8f

typedef __attribute__((ext_vector_type(8))) short bf16x8;
typedef __attribute__((ext_vector_type(4))) float f32x4;

__device__ __forceinline__ float load_ext(const void* p, size_t idx, int isf32) {
  if (isf32) return ((const float*)p)[idx];
  unsigned short u = ((const unsigned short*)p)[idx];
  union { unsigned int i; float f; } v;
  v.i = ((unsigned int)u) << 16;
  return v.f;
}

// ---- dtype probe (proven r3-r11): flag=1 => external data is fp32 ----
__global__ void fsc_probe_dtype_k(const unsigned short* __restrict__ w2raw,
                                  int nelems, int* __restrict__ flag) {
  __shared__ int cnt;
  if (threadIdx.x == 0) cnt = 0;
  __syncthreads();
  int local = 0;
  for (int i = threadIdx.x; i < nelems; i += 256) {
    unsigned short u = w2raw[i];
    int ex = (u >> 7) & 0xFF;
    if (ex != 0 && (ex < 0x69 || ex > 0x84)) local++;
  }
  atomicAdd(&cnt, local);
  __syncthreads();
  if (threadIdx.x == 0) *flag = (cnt > nelems / 8) ? 1 : 0;
}

// ---- conv1 NHWC4 weight repack: [s=2][t=4][lane=64][j=8] bf16 (proven r10) ----
__global__ void fsc_repack_w1m_k(const void* __restrict__ W,
                                 __hip_bfloat16* __restrict__ Wf,
                                 const int* __restrict__ flag) {
  const int isf32 = *flag;
  int i = blockIdx.x * blockDim.x + threadIdx.x;
  if (i >= 4096) return;
  int j = i & 7;
  int lane = (i >> 3) & 63;
  int t = (i >> 9) & 3;
  int s = i >> 11;
  int kk = (lane >> 4) * 8 + j;
  int co = t * 16 + (lane & 15);
  float v = 0.f;
  int kh, kwp, ci;
  bool live = false;
  if (s == 0) { kh = kk >> 4; kwp = (kk & 15) >> 2; ci = kk & 3; live = true; }
  else if (kk < 16) { kh = 2; kwp = kk >> 2; ci = kk & 3; live = true; }
  if (live && kwp < 3 && ci < 3)
    v = load_ext(W, (size_t)((co * 3 + ci) * 3 + kh) * 3 + kwp, isf32);
  Wf[i] = __float2bfloat16(v);
}

// ---- conv2/3/4 weight repack: OIHW [64][64][3][3] -> bf16 A-frag order ----
__global__ void fsc_repack_wm_k(const void* __restrict__ W,
                                __hip_bfloat16* __restrict__ Wf,
                                const int* __restrict__ flag) {
  const int isf32 = *flag;
  int o = blockIdx.x * blockDim.x + threadIdx.x;
  if (o >= 36864) return;
  int j = o & 7;
  int lane = (o >> 3) & 63;
  int t = (o >> 9) & 3;
  int kk = o >> 11;       // 0..17
  int s = kk & 1;
  int khw = kk >> 1;      // kh*3+kw
  int kh = khw / 3, kw = khw - kh * 3;
  int co = t * 16 + (lane & 15);
  int ci = s * 32 + (lane >> 4) * 8 + j;
  float v = load_ext(W, (size_t)((co * 64 + ci) * 3 + kh) * 3 + kw, isf32);
  Wf[o] = __float2bfloat16(v);
}

// ---- zero the 1-px border of an NHWC-padded [N][P][P][64] bf16 buffer ----
template <int P>
__global__ void fsc_zero_border_k(__hip_bfloat16* __restrict__ buf, int N) {
  int i = blockIdx.x * blockDim.x + threadIdx.x;
  const int RP = 4 * P - 4;
  if (i >= N * RP * 64) return;
  int c = i & 63;
  int r = (i >> 6) % RP;
  int n = (i >> 6) / RP;
  int row, colp;
  if (r < P) { row = 0; colp = r; }
  else if (r < 2 * P) { row = P - 1; colp = r - P; }
  else if (r < 3 * P - 2) { row = r - 2 * P + 1; colp = 0; }
  else { row = r - (3 * P - 2) + 1; colp = P - 1; }
  buf[(((size_t)n * P + row) * P + colp) * 64 + c] = __float2bfloat16(0.f);
}

// ---- zero X's pad cells: rows 84..85 (all w) + cols 84..85 (h<84), 4 ch ----
__global__ void fsc_zero_xb_k(__hip_bfloat16* __restrict__ X, int N) {
  int i = blockIdx.x * blockDim.x + threadIdx.x;
  if (i >= N * 1360) return;  // (2*86 + 84*2) * 4
  int c = i & 3;
  int p = (i >> 2) % 340;
  int n = (i >> 2) / 340;
  int h, w;
  if (p < 172) { h = 84 + (p / 86); w = p % 86; }
  else { int pp = p - 172; h = pp >> 1; w = 84 + (pp & 1); }
  X[(((size_t)n * 86 + h) * 86 + w) * 4 + c] = __float2bfloat16(0.f);
}

// ---- input transform: ext [img][3][84][84] -> bf16 NHWC4 [img][86][86][4] ----
__global__ void fsc_xform1_k(const void* __restrict__ x, int srcImg0,
                             __hip_bfloat16* __restrict__ X, int dstImg0,
                             int n, const int* __restrict__ flag) {
  const int isf32 = *flag;
  int i = blockIdx.x * blockDim.x + threadIdx.x;
  const int imgL = i / 7056;
  if (imgL >= n) return;
  const int sp = i - imgL * 7056;
  const int h = sp / 84, w = sp - h * 84;
  const size_t base = (size_t)(srcImg0 + imgL) * 21168;
  union { unsigned short u[4]; uint2 q; } pk;
#pragma unroll
  for (int ci = 0; ci < 3; ++ci)
    pk.u[ci] = __bfloat16_as_ushort(__float2bfloat16(load_ext(x, base + ci * 7056 + sp, isf32)));
  pk.u[3] = 0;
  *(uint2*)(void*)(X + (((size_t)(dstImg0 + imgL) * 86 + h) * 86 + w) * 4) = pk.q;
}

// ---- conv1 MFMA (NHWC4 input; proven r10): 64 cols/wave, 2 k-steps ----
__global__ void fsc_conv1m_k(const __hip_bfloat16* __restrict__ X,
                             const __hip_bfloat16* __restrict__ Wf,
                             const void* __restrict__ bias,
                             __hip_bfloat16* __restrict__ out, int N,
                             const int* __restrict__ flag) {
  constexpr int TPI = 28;  // ceil(1764/64)
  const int wid = blockIdx.x * 4 + (threadIdx.x >> 6);
  const int img = wid / TPI;
  if (img >= N) return;
  const int tl = wid - img * TPI;
  const int lane = threadIdx.x & 63;
  const int nidx = lane & 15, quad = lane >> 4;

  int col[4];
  bool val[4];
  int hoA[4], woA[4];
#pragma unroll
  for (int p = 0; p < 4; ++p) {
    col[p] = tl * 64 + p * 16 + nidx;
    val[p] = col[p] < 1764;
    if (!val[p]) col[p] = 1763;
    hoA[p] = col[p] / 42;
    woA[p] = col[p] - hoA[p] * 42;
  }

  f32x4 acc[4][4];
#pragma unroll
  for (int p = 0; p < 4; ++p)
#pragma unroll
    for (int t = 0; t < 4; ++t) acc[p][t] = (f32x4){0.f, 0.f, 0.f, 0.f};

#pragma unroll
  for (int s = 0; s < 2; ++s) {
    bf16x8 b[4];
#pragma unroll
    for (int p = 0; p < 4; ++p) {
      const int hi = 2 * hoA[p] + (s == 0 ? (quad >> 1) : 2);
      const __hip_bfloat16* bp =
          X + (((size_t)img * 86 + hi) * 86 + 2 * woA[p]) * 4 + (quad & 1) * 8;
      b[p] = *(const bf16x8*)(const void*)bp;
    }
#pragma unroll
    for (int t = 0; t < 4; ++t) {
      bf16x8 a = *(const bf16x8*)(const void*)(Wf + ((size_t)(s * 4 + t) * 64 + lane) * 8);
#pragma unroll
      for (int p = 0; p < 4; ++p)
        acc[p][t] = __builtin_amdgcn_mfma_f32_16x16x32_bf16(a, b[p], acc[p][t], 0, 0, 0);
    }
  }

  const int isf32 = *flag;
#pragma unroll
  for (int p = 0; p < 4; ++p) {
#pragma unroll
    for (int t = 0; t < 4; ++t) {
      float v[4];
#pragma unroll
      for (int r = 0; r < 4; ++r) {
        const int cout = t * 16 + quad * 4 + r;
        float xv = acc[p][t][r] + load_ext(bias, cout, isf32);
        v[r] = xv > 0.f ? xv : 0.f;
      }
      if (val[p]) {
        __hip_bfloat16* o = out + (((size_t)img * 44 + (hoA[p] + 1)) * 44 +
                                   (woA[p] + 1)) * 64 + t * 16 + quad * 4;
        union { unsigned short u[4]; uint2 w; } pk;
#pragma unroll
        for (int r = 0; r < 4; ++r) pk.u[r] = __bfloat16_as_ushort(__float2bfloat16(v[r]));
        *(uint2*)(void*)o = pk.w;
      }
    }
  }
}

// ---- implicit-GEMM conv, CG*16 cols x 64 couts, depth-4 rotating B prefetch ----
template <int HO, int PWI, int PWO, int ROFF, int CG>
__global__ void fsc_convp_k(const __hip_bfloat16* __restrict__ in,
                            const __hip_bfloat16* __restrict__ Wf,
                            const void* __restrict__ bias,
                            __hip_bfloat16* __restrict__ out, int N,
                            const int* __restrict__ flag) {
  constexpr int COLS = CG * 16;
  constexpr int TPI = (HO * HO + COLS - 1) / COLS;
  const int wid = blockIdx.x * 4 + (threadIdx.x >> 6);
  const int img = wid / TPI;
  if (img >= N) return;
  const int tl = wid - img * TPI;
  const int lane = threadIdx.x & 63;
  const int nidx = lane & 15, quad = lane >> 4;

  int col[CG];
  bool val[CG];
  int hoA[CG], woA[CG];
  const __hip_bfloat16* bsrc[CG];
#pragma unroll
  for (int p = 0; p < CG; ++p) {
    col[p] = tl * COLS + p * 16 + nidx;
    val[p] = col[p] < HO * HO;
    if (!val[p]) col[p] = HO * HO - 1;
    hoA[p] = col[p] / HO;
    woA[p] = col[p] - hoA[p] * HO;
    bsrc[p] = in + (((size_t)img * PWI + (2 * hoA[p] + ROFF)) * PWI +
                    (2 * woA[p] + ROFF)) * 64 + quad * 8;
  }
  const __hip_bfloat16* asrc = Wf + lane * 8;

  f32x4 acc[CG][4];
#pragma unroll
  for (int p = 0; p < CG; ++p)
#pragma unroll
    for (int t = 0; t < 4; ++t) acc[p][t] = (f32x4){0.f, 0.f, 0.f, 0.f};

  // boff(kk): s=kk&1, khw=kk>>1 -> (kh*PWI+kw)*64 + s*32  (compile-time per step)
#define FSC_BOFF(kk) ((((kk) >> 1) / 3 * PWI + ((kk) >> 1) % 3) * 64 + ((kk)&1) * 32)

  bf16x8 bbuf[4][CG];
#pragma unroll
  for (int d = 0; d < 3; ++d)
#pragma unroll
    for (int p = 0; p < CG; ++p)
      bbuf[d][p] = *(const bf16x8*)(const void*)(bsrc[p] + FSC_BOFF(d));

#pragma unroll
  for (int kk = 0; kk < 18; ++kk) {
    if (kk + 3 < 18) {
#pragma unroll
      for (int p = 0; p < CG; ++p)
        bbuf[(kk + 3) & 3][p] =
            *(const bf16x8*)(const void*)(bsrc[p] + FSC_BOFF(kk + 3));
    }
#pragma unroll
    for (int t = 0; t < 4; ++t) {
      bf16x8 a = *(const bf16x8*)(const void*)(asrc + (kk * 4 + t) * 512);
#pragma unroll
      for (int p = 0; p < CG; ++p)
        acc[p][t] =
            __builtin_amdgcn_mfma_f32_16x16x32_bf16(a, bbuf[kk & 3][p], acc[p][t], 0, 0, 0);
    }
  }
#undef FSC_BOFF

  const int isf32 = *flag;
#pragma unroll
  for (int p = 0; p < CG; ++p) {
#pragma unroll
    for (int t = 0; t < 4; ++t) {
      float v[4];
#pragma unroll
      for (int r = 0; r < 4; ++r) {
        const int cout = t * 16 + quad * 4 + r;
        float xv = acc[p][t][r] + load_ext(bias, cout, isf32);
        v[r] = xv > 0.f ? xv : 0.f;
      }
      if (val[p]) {
        __hip_bfloat16* o = out + (((size_t)img * PWO + (hoA[p] + 1)) * PWO +
                                   (woA[p] + 1)) * 64 + t * 16 + quad * 4;
        union { unsigned short u[4]; uint2 w; } pk;
#pragma unroll
        for (int r = 0; r < 4; ++r) pk.u[r] = __bfloat16_as_ushort(__float2bfloat16(v[r]));
        *(uint2*)(void*)o = pk.w;
      }
    }
  }
}

// ---- 32-col MFMA conv, EMB output (conv4; proven r6-r11) ----
__global__ void fsc_conv4_k(const __hip_bfloat16* __restrict__ in,
                            const __hip_bfloat16* __restrict__ Wf,
                            const void* __restrict__ bias, float* __restrict__ emb,
                            int N, const int* __restrict__ flag) {
  constexpr int HO = 6, PWI = 13;
  constexpr int TPI = 2;  // ceil(36/32)
  const int wid = blockIdx.x * 4 + (threadIdx.x >> 6);
  const int img = wid / TPI;
  if (img >= N) return;
  const int tl = wid - img * TPI;
  const int lane = threadIdx.x & 63;
  const int nidx = lane & 15, quad = lane >> 4;

  int col0 = tl * 32 + nidx;
  int col1 = col0 + 16;
  const bool val0 = col0 < HO * HO;
  const bool val1 = col1 < HO * HO;
  if (!val0) col0 = HO * HO - 1;
  if (!val1) col1 = HO * HO - 1;
  const int ho0 = col0 / HO, wo0 = col0 - ho0 * HO;
  const int ho1 = col1 / HO, wo1 = col1 - ho1 * HO;

  const __hip_bfloat16* bsrc0 =
      in + (((size_t)img * PWI + 2 * ho0) * PWI + 2 * wo0) * 64 + quad * 8;
  const __hip_bfloat16* bsrc1 =
      in + (((size_t)img * PWI + 2 * ho1) * PWI + 2 * wo1) * 64 + quad * 8;
  const __hip_bfloat16* asrc = Wf + lane * 8;

  f32x4 acc[2][4];
#pragma unroll
  for (int p = 0; p < 2; ++p)
#pragma unroll
    for (int t = 0; t < 4; ++t) acc[p][t] = (f32x4){0.f, 0.f, 0.f, 0.f};

#pragma unroll
  for (int kk = 0; kk < 18; ++kk) {
    const int s = kk & 1;
    const int khw = kk >> 1;
    const int kh = khw / 3, kw = khw - kh * 3;
    const int boff = (kh * PWI + kw) * 64 + s * 32;
    bf16x8 b0 = *(const bf16x8*)(const void*)(bsrc0 + boff);
    bf16x8 b1 = *(const bf16x8*)(const void*)(bsrc1 + boff);
#pragma unroll
    for (int t = 0; t < 4; ++t) {
      bf16x8 a = *(const bf16x8*)(const void*)(asrc + (kk * 4 + t) * 512);
      acc[0][t] = __builtin_amdgcn_mfma_f32_16x16x32_bf16(a, b0, acc[0][t], 0, 0, 0);
      acc[1][t] = __builtin_amdgcn_mfma_f32_16x16x32_bf16(a, b1, acc[1][t], 0, 0, 0);
    }
  }

  const int isf32 = *flag;
#pragma unroll
  for (int p = 0; p < 2; ++p) {
    const bool valid = p == 0 ? val0 : val1;
    const int col = p == 0 ? col0 : col1;
#pragma unroll
    for (int t = 0; t < 4; ++t) {
      float v[4];
#pragma unroll
      for (int r = 0; r < 4; ++r) {
        const int cout = t * 16 + quad * 4 + r;
        float xv = acc[p][t][r] + load_ext(bias, cout, isf32);
        v[r] = xv > 0.f ? xv : 0.f;
      }
      if (valid) {
        float* o = emb + ((size_t)img * 36 + col) * 64 + t * 16 + quad * 4;
        *(f32x4*)(void*)o = (f32x4){v[0], v[1], v[2], v[3]};
      }
    }
  }
}

// ---- head (proven r3-r11) ----
__global__ void fsc_proto_k(const float* __restrict__ emb_s, const int* __restrict__ y,
                            float* __restrict__ protos) {
  int i = blockIdx.x * blockDim.x + threadIdx.x;
  if (i >= BB * CC * DD) return;
  int d = i % DD;
  int bc = i / DD;
  int c = bc % CC;
  int b = bc / CC;
  float sum = 0.f;
  for (int s = 0; s < SS; ++s) {
    if (y[b * SS + s] % CC == c) sum += emb_s[(size_t)(b * SS + s) * DD + d];
  }
  protos[i] = sum * 0.2f;
}

__global__ void fsc_pnorm_k(const float* __restrict__ protos, float* __restrict__ pn) {
  __shared__ float red[4];
  __shared__ float inv;
  const int bc = blockIdx.x;
  const float* p = protos + (size_t)bc * DD;
  float ss = 0.f;
  for (int d = threadIdx.x; d < DD; d += 256) { float v = p[d]; ss += v * v; }
#pragma unroll
  for (int off = 32; off > 0; off >>= 1) ss += __shfl_down(ss, off);
  if ((threadIdx.x & 63) == 0) red[threadIdx.x >> 6] = ss;
  __syncthreads();
  if (threadIdx.x == 0) {
    float nrm = sqrtf(red[0] + red[1] + red[2] + red[3]);
    nrm = nrm > EPSF ? nrm : EPSF;
    inv = 1.f / nrm;
  }
  __syncthreads();
  float sc = inv;
  for (int d = threadIdx.x; d < DD; d += 256) pn[(size_t)bc * DD + d] = p[d] * sc;
}

__global__ void fsc_preds_k(const float* __restrict__ emb_t, const float* __restrict__ pn,
                            void* __restrict__ out, const int* __restrict__ flag) {
  __shared__ float red[4][6];
  __shared__ float fin[6];
  const int isf32 = *flag;
  const int bt = blockIdx.x;
  const int b = bt / TT;
  const float* et = emb_t + (size_t)bt * DD;
  float e[9];
#pragma unroll
  for (int k = 0; k < 9; ++k) e[k] = et[threadIdx.x + 256 * k];
  float vals[6];
  {
    float ss = 0.f;
#pragma unroll
    for (int k = 0; k < 9; ++k) ss += e[k] * e[k];
    vals[0] = ss;
  }
  const float* pb = pn + (size_t)b * CC * DD;
#pragma unroll
  for (int c = 0; c < CC; ++c) {
    float s = 0.f;
#pragma unroll
    for (int k = 0; k < 9; ++k) s += e[k] * pb[(size_t)c * DD + threadIdx.x + 256 * k];
    vals[1 + c] = s;
  }
#pragma unroll
  for (int v = 0; v < 6; ++v) {
#pragma unroll
    for (int off = 32; off > 0; off >>= 1) vals[v] += __shfl_down(vals[v], off);
  }
  if ((threadIdx.x & 63) == 0) {
#pragma unroll
    for (int v = 0; v < 6; ++v) red[threadIdx.x >> 6][v] = vals[v];
  }
  __syncthreads();
  if (threadIdx.x < 6)
    fin[threadIdx.x] = red[0][threadIdx.x] + red[1][threadIdx.x] +
                       red[2][threadIdx.x] + red[3][threadIdx.x];
  __syncthreads();
  if (threadIdx.x < CC) {
    float nt = sqrtf(fin[0]);
    nt = nt > EPSF ? nt : EPSF;
    float r = fin[1 + threadIdx.x] / nt;
    if (isf32) ((float*)out)[(size_t)bt * CC + threadIdx.x] = r;
    else ((__hip_bfloat16*)out)[(size_t)bt * CC + threadIdx.x] = __float2bfloat16(r);
  }
}

static inline int fsc_cdiv(int a, int b) { return (a + b - 1) / b; }
static inline int imin(int a, int b) { return a < b ? a : b; }
static inline int imax(int a, int b) { return a > b ? a : b; }

extern "C" void kernel_launch(void* const* d_in, const int* in_sizes, int n_in,
                              void* d_out, int out_size, void* d_ws, size_t ws_size,
                              hipStream_t stream) {
  const void* xs = d_in[0];
  const void* xt = d_in[1];
  const int* y = (const int*)d_in[2];
  const void* W1 = d_in[3];
  const void* b1 = d_in[4];
  const void* W2 = d_in[5];
  const void* b2 = d_in[6];
  const void* W3 = d_in[7];
  const void* b3 = d_in[8];
  const void* W4 = d_in[9];
  const void* b4 = d_in[10];

  // ---- workspace layout: fixed ~25.6 MB + X/A1/A2 chunk buffers ----
  char* w = (char*)d_ws;
  int* flag = (int*)w;                      w += 256;
  __hip_bfloat16* Wf1 = (__hip_bfloat16*)w; w += 4096 * 2;
  __hip_bfloat16* Wf2 = (__hip_bfloat16*)w; w += 36864 * 2;
  __hip_bfloat16* Wf3 = (__hip_bfloat16*)w; w += 36864 * 2;
  __hip_bfloat16* Wf4 = (__hip_bfloat16*)w; w += 36864 * 2;
  float* protos = (float*)w;                w += (size_t)BB * CC * DD * 4;
  float* pn = (float*)w;                    w += (size_t)BB * CC * DD * 4;
  float* emb = (float*)w;                   w += (size_t)NTOT * DD * 4;           // 7.37 MB
  __hip_bfloat16* C3 = (__hip_bfloat16*)w;  w += (size_t)NTOT * 13 * 13 * 64 * 2; // 17.3 MB
  char* chunk0 = w;
  const size_t fixedB = (size_t)(w - (char*)d_ws);
  const size_t szX  = (size_t)86 * 86 * 4 * 2;    //  59,168 B/img
  const size_t szA1 = (size_t)44 * 44 * 64 * 2;   // 247,808 B/img
  const size_t szA2 = (size_t)23 * 23 * 64 * 2;   //  67,712 B/img
  const size_t perImgB = szX + szA1 + szA2;        // 374,688 B/img

  int CH = 50;
  const int cands[7] = {640, 600, 512, 400, 200, 100, 50};
  for (int k = 0; k < 7; ++k) {
    if (fixedB + (size_t)cands[k] * perImgB <= ws_size) { CH = cands[k]; break; }
  }
  __hip_bfloat16* X  = (__hip_bfloat16*)chunk0;
  __hip_bfloat16* A1 = (__hip_bfloat16*)(chunk0 + (size_t)CH * szX);
  __hip_bfloat16* A2 = (__hip_bfloat16*)(chunk0 + (size_t)CH * (szX + szA1));

  // 1. dtype probe + weight repacks
  fsc_probe_dtype_k<<<1, 256, 0, stream>>>((const unsigned short*)W2, 64 * 64 * 9, flag);
  fsc_repack_w1m_k<<<fsc_cdiv(4096, 256), 256, 0, stream>>>(W1, Wf1, flag);
  fsc_repack_wm_k<<<fsc_cdiv(36864, 256), 256, 0, stream>>>(W2, Wf2, flag);
  fsc_repack_wm_k<<<fsc_cdiv(36864, 256), 256, 0, stream>>>(W3, Wf3, flag);
  fsc_repack_wm_k<<<fsc_cdiv(36864, 256), 256, 0, stream>>>(W4, Wf4, flag);

  // 2. zero pad cells (interiors rewritten each chunk; pads stay 0)
  fsc_zero_xb_k<<<fsc_cdiv(CH * 1360, 256), 256, 0, stream>>>(X, CH);
  fsc_zero_border_k<44><<<fsc_cdiv(CH * (4 * 44 - 4) * 64, 256), 256, 0, stream>>>(A1, CH);
  fsc_zero_border_k<23><<<fsc_cdiv(CH * (4 * 23 - 4) * 64, 256), 256, 0, stream>>>(A2, CH);
  fsc_zero_border_k<13><<<fsc_cdiv(NTOT * (4 * 13 - 4) * 64, 256), 256, 0, stream>>>(C3, NTOT);

  // 3. chunks over GLOBAL image index (support 0..199, target 200..799)
  for (int g0 = 0; g0 < NTOT; g0 += CH) {
    const int n = imin(CH, NTOT - g0);
    if (g0 < NSUP) {
      const int cnt = imin(g0 + n, NSUP) - g0;
      fsc_xform1_k<<<fsc_cdiv(cnt * 7056, 256), 256, 0, stream>>>(
          xs, g0, X, 0, cnt, flag);
    }
    if (g0 + n > NSUP) {
      const int tStart = imax(g0, NSUP);
      const int cnt = g0 + n - tStart;
      fsc_xform1_k<<<fsc_cdiv(cnt * 7056, 256), 256, 0, stream>>>(
          xt, tStart - NSUP, X, tStart - g0, cnt, flag);
    }
    // conv1: NHWC4 -> 42x42 into 44-pad; TPI=28
    fsc_conv1m_k<<<fsc_cdiv(n * 28, 4), 256, 0, stream>>>(X, Wf1, b1, A1, n, flag);
    // conv2: 44-pad -> 21x21 into 23-pad; ROFF=1; 32 cols (TPI=14), prefetch
    fsc_convp_k<21, 44, 23, 1, 2><<<fsc_cdiv(n * 14, 4), 256, 0, stream>>>(
        A1, Wf2, b2, A2, n, flag);
    // conv3: 23-pad -> 11x11 into 13-pad; ROFF=0; 16 cols (TPI=8), prefetch
    fsc_convp_k<11, 23, 13, 0, 1><<<fsc_cdiv(n * 8, 4), 256, 0, stream>>>(
        A2, Wf3, b3, C3 + (size_t)g0 * 13 * 13 * 64, n, flag);
  }

  // 4. conv4 full batch: 13-pad -> fp32 emb [800][2304]
  fsc_conv4_k<<<fsc_cdiv(NTOT * 2, 4), 256, 0, stream>>>(C3, Wf4, b4, emb, NTOT, flag);

  // 5. head
  fsc_proto_k<<<fsc_cdiv(BB * CC * DD, 256), 256, 0, stream>>>(emb, y, protos);
  fsc_pnorm_k<<<BB * CC, 256, 0, stream>>>(protos, pn);
  fsc_preds_k<<<NTGT, 256, 0, stream>>>(emb + (size_t)NSUP * DD, pn, d_out, flag);
}

// Round 13
// 429.584 us; speedup vs baseline: 1.1294x; 1.0380x over previous
//
#include <hip/hip_runtime.h>
#include <hip/hip_bf16.h>

// Few-shot matching-network head + Conv4 backbone (MI355X, gfx950). Round 13.
//
// R12: 446 us. conv2 traffic is compulsory (FETCH 142MB = A1 once) but BW
// stuck at 2.3 TB/s: B-loads touch 16 distinct 64B lines at 256B stride per
// 16-lane group (NHWC-64 + stride2). conv1m, whose quad-groups read CONTIGUOUS
// 256B, moves the same MB/chunk and never shows in top-5 -> line-scatter
// throttles TA/L1. Fix: A1 stored as [img][plane=cg*2+wparity][44][22][8ch]
// planes; conv2 tap (kh,kw) then reads 16 consecutive 16B chunks per
// quad-group (contiguous 256B). Changes: conv1 epilogue, plane zero kernel,
// conv2 B-addressing. conv3/conv4/head proven r10-r12 (absmax 0.0039).

#define BB 8
#define SS 25
#define TT 75
#define CC 5
#define DD 2304
#define NSUP 200
#define NTGT 600
#define NTOT 800
#define EPSF 1e-8f

// A1 plane layout constants
#define PLE 7744       // plane elems: 44*22*8
#define IMG1E 123904   // img elems: 16*7744

typedef __attribute__((ext_vector_type(8))) short bf16x8;
typedef __attribute__((ext_vector_type(4))) float f32x4;

__device__ __forceinline__ float load_ext(const void* p, size_t idx, int isf32) {
  if (isf32) return ((const float*)p)[idx];
  unsigned short u = ((const unsigned short*)p)[idx];
  union { unsigned int i; float f; } v;
  v.i = ((unsigned int)u) << 16;
  return v.f;
}

// ---- dtype probe (proven r3-r12): flag=1 => external data is fp32 ----
__global__ void fsc_probe_dtype_k(const unsigned short* __restrict__ w2raw,
                                  int nelems, int* __restrict__ flag) {
  __shared__ int cnt;
  if (threadIdx.x == 0) cnt = 0;
  __syncthreads();
  int local = 0;
  for (int i = threadIdx.x; i < nelems; i += 256) {
    unsigned short u = w2raw[i];
    int ex = (u >> 7) & 0xFF;
    if (ex != 0 && (ex < 0x69 || ex > 0x84)) local++;
  }
  atomicAdd(&cnt, local);
  __syncthreads();
  if (threadIdx.x == 0) *flag = (cnt > nelems / 8) ? 1 : 0;
}

// ---- conv1 NHWC4 weight repack: [s=2][t=4][lane=64][j=8] bf16 (proven r10) ----
__global__ void fsc_repack_w1m_k(const void* __restrict__ W,
                                 __hip_bfloat16* __restrict__ Wf,
                                 const int* __restrict__ flag) {
  const int isf32 = *flag;
  int i = blockIdx.x * blockDim.x + threadIdx.x;
  if (i >= 4096) return;
  int j = i & 7;
  int lane = (i >> 3) & 63;
  int t = (i >> 9) & 3;
  int s = i >> 11;
  int kk = (lane >> 4) * 8 + j;
  int co = t * 16 + (lane & 15);
  float v = 0.f;
  int kh, kwp, ci;
  bool live = false;
  if (s == 0) { kh = kk >> 4; kwp = (kk & 15) >> 2; ci = kk & 3; live = true; }
  else if (kk < 16) { kh = 2; kwp = kk >> 2; ci = kk & 3; live = true; }
  if (live && kwp < 3 && ci < 3)
    v = load_ext(W, (size_t)((co * 3 + ci) * 3 + kh) * 3 + kwp, isf32);
  Wf[i] = __float2bfloat16(v);
}

// ---- conv2/3/4 weight repack: OIHW [64][64][3][3] -> bf16 A-frag order ----
__global__ void fsc_repack_wm_k(const void* __restrict__ W,
                                __hip_bfloat16* __restrict__ Wf,
                                const int* __restrict__ flag) {
  const int isf32 = *flag;
  int o = blockIdx.x * blockDim.x + threadIdx.x;
  if (o >= 36864) return;
  int j = o & 7;
  int lane = (o >> 3) & 63;
  int t = (o >> 9) & 3;
  int kk = o >> 11;       // 0..17
  int s = kk & 1;
  int khw = kk >> 1;      // kh*3+kw
  int kh = khw / 3, kw = khw - kh * 3;
  int co = t * 16 + (lane & 15);
  int ci = s * 32 + (lane >> 4) * 8 + j;
  float v = load_ext(W, (size_t)((co * 64 + ci) * 3 + kh) * 3 + kw, isf32);
  Wf[o] = __float2bfloat16(v);
}

// ---- zero the 1-px border of an NHWC-padded [N][P][P][64] bf16 buffer ----
template <int P>
__global__ void fsc_zero_border_k(__hip_bfloat16* __restrict__ buf, int N) {
  int i = blockIdx.x * blockDim.x + threadIdx.x;
  const int RP = 4 * P - 4;
  if (i >= N * RP * 64) return;
  int c = i & 63;
  int r = (i >> 6) % RP;
  int n = (i >> 6) / RP;
  int row, colp;
  if (r < P) { row = 0; colp = r; }
  else if (r < 2 * P) { row = P - 1; colp = r - P; }
  else if (r < 3 * P - 2) { row = r - 2 * P + 1; colp = 0; }
  else { row = r - (3 * P - 2) + 1; colp = P - 1; }
  buf[(((size_t)n * P + row) * P + colp) * 64 + c] = __float2bfloat16(0.f);
}

// ---- zero A1-plane pad cells: h in {0,43} all w2; plus the never-written
//      column (wp==0 -> w2=0 [w'=0]; wp==1 -> w2=21 [w'=43]) for h=1..42 ----
__global__ void fsc_zero_a1p_k(__hip_bfloat16* __restrict__ A1, int N) {
  int i = blockIdx.x * blockDim.x + threadIdx.x;
  if (i >= N * 16 * 86 * 8) return;
  int ch = i & 7;
  int q = (i >> 3) % 86;
  int pl = ((i >> 3) / 86) % 16;
  int n = (i >> 3) / (86 * 16);
  const int wp = pl & 1;
  int h, w2;
  if (q < 22) { h = 0; w2 = q; }
  else if (q < 44) { h = 43; w2 = q - 22; }
  else { h = q - 43; w2 = wp ? 21 : 0; }  // h = 1..42
  A1[(size_t)n * IMG1E + pl * PLE + (h * 22 + w2) * 8 + ch] = __float2bfloat16(0.f);
}

// ---- zero X's pad cells: rows 84..85 (all w) + cols 84..85 (h<84), 4 ch ----
__global__ void fsc_zero_xb_k(__hip_bfloat16* __restrict__ X, int N) {
  int i = blockIdx.x * blockDim.x + threadIdx.x;
  if (i >= N * 1360) return;  // (2*86 + 84*2) * 4
  int c = i & 3;
  int p = (i >> 2) % 340;
  int n = (i >> 2) / 340;
  int h, w;
  if (p < 172) { h = 84 + (p / 86); w = p % 86; }
  else { int pp = p - 172; h = pp >> 1; w = 84 + (pp & 1); }
  X[(((size_t)n * 86 + h) * 86 + w) * 4 + c] = __float2bfloat16(0.f);
}

// ---- input transform: ext [img][3][84][84] -> bf16 NHWC4 [img][86][86][4] ----
__global__ void fsc_xform1_k(const void* __restrict__ x, int srcImg0,
                             __hip_bfloat16* __restrict__ X, int dstImg0,
                             int n, const int* __restrict__ flag) {
  const int isf32 = *flag;
  int i = blockIdx.x * blockDim.x + threadIdx.x;
  const int imgL = i / 7056;
  if (imgL >= n) return;
  const int sp = i - imgL * 7056;
  const int h = sp / 84, w = sp - h * 84;
  const size_t base = (size_t)(srcImg0 + imgL) * 21168;
  union { unsigned short u[4]; uint2 q; } pk;
#pragma unroll
  for (int ci = 0; ci < 3; ++ci)
    pk.u[ci] = __bfloat16_as_ushort(__float2bfloat16(load_ext(x, base + ci * 7056 + sp, isf32)));
  pk.u[3] = 0;
  *(uint2*)(void*)(X + (((size_t)(dstImg0 + imgL) * 86 + h) * 86 + w) * 4) = pk.q;
}

// ---- conv1 MFMA (NHWC4 input; proven r10), epilogue -> A1 PLANE layout ----
__global__ void fsc_conv1m_k(const __hip_bfloat16* __restrict__ X,
                             const __hip_bfloat16* __restrict__ Wf,
                             const void* __restrict__ bias,
                             __hip_bfloat16* __restrict__ out, int N,
                             const int* __restrict__ flag) {
  constexpr int TPI = 28;  // ceil(1764/64)
  const int wid = blockIdx.x * 4 + (threadIdx.x >> 6);
  const int img = wid / TPI;
  if (img >= N) return;
  const int tl = wid - img * TPI;
  const int lane = threadIdx.x & 63;
  const int nidx = lane & 15, quad = lane >> 4;

  int col[4];
  bool val[4];
  int hoA[4], woA[4];
#pragma unroll
  for (int p = 0; p < 4; ++p) {
    col[p] = tl * 64 + p * 16 + nidx;
    val[p] = col[p] < 1764;
    if (!val[p]) col[p] = 1763;
    hoA[p] = col[p] / 42;
    woA[p] = col[p] - hoA[p] * 42;
  }

  f32x4 acc[4][4];
#pragma unroll
  for (int p = 0; p < 4; ++p)
#pragma unroll
    for (int t = 0; t < 4; ++t) acc[p][t] = (f32x4){0.f, 0.f, 0.f, 0.f};

#pragma unroll
  for (int s = 0; s < 2; ++s) {
    bf16x8 b[4];
#pragma unroll
    for (int p = 0; p < 4; ++p) {
      const int hi = 2 * hoA[p] + (s == 0 ? (quad >> 1) : 2);
      const __hip_bfloat16* bp =
          X + (((size_t)img * 86 + hi) * 86 + 2 * woA[p]) * 4 + (quad & 1) * 8;
      b[p] = *(const bf16x8*)(const void*)bp;
    }
#pragma unroll
    for (int t = 0; t < 4; ++t) {
      bf16x8 a = *(const bf16x8*)(const void*)(Wf + ((size_t)(s * 4 + t) * 64 + lane) * 8);
#pragma unroll
      for (int p = 0; p < 4; ++p)
        acc[p][t] = __builtin_amdgcn_mfma_f32_16x16x32_bf16(a, b[p], acc[p][t], 0, 0, 0);
    }
  }

  const int isf32 = *flag;
#pragma unroll
  for (int p = 0; p < 4; ++p) {
    const int h = hoA[p] + 1;
    const int wq = woA[p] + 1;
    const int wp = wq & 1, w2 = wq >> 1;
#pragma unroll
    for (int t = 0; t < 4; ++t) {
      float v[4];
#pragma unroll
      for (int r = 0; r < 4; ++r) {
        const int cout = t * 16 + quad * 4 + r;
        float xv = acc[p][t][r] + load_ext(bias, cout, isf32);
        v[r] = xv > 0.f ? xv : 0.f;
      }
      if (val[p]) {
        // plane = cg*2+wp, cg = 2t + (quad>>1); within-pixel ch = (quad&1)*4
        __hip_bfloat16* o = out + (size_t)img * IMG1E +
                            ((2 * t + (quad >> 1)) * 2 + wp) * PLE +
                            (h * 22 + w2) * 8 + (quad & 1) * 4;
        union { unsigned short u[4]; uint2 w; } pk;
#pragma unroll
        for (int r = 0; r < 4; ++r) pk.u[r] = __bfloat16_as_ushort(__float2bfloat16(v[r]));
        *(uint2*)(void*)o = pk.w;
      }
    }
  }
}

// ---- conv2 from A1 planes: 32 cols x 64 couts, depth-4 B prefetch.
//      Quad-group loads are 256B CONTIGUOUS (16 consecutive 16B chunks). ----
__global__ void fsc_conv2p_k(const __hip_bfloat16* __restrict__ A1,
                             const __hip_bfloat16* __restrict__ Wf,
                             const void* __restrict__ bias,
                             __hip_bfloat16* __restrict__ out, int N,
                             const int* __restrict__ flag) {
  constexpr int TPI = 14;  // ceil(441/32)
  const int wid = blockIdx.x * 4 + (threadIdx.x >> 6);
  const int img = wid / TPI;
  if (img >= N) return;
  const int tl = wid - img * TPI;
  const int lane = threadIdx.x & 63;
  const int nidx = lane & 15, quad = lane >> 4;

  int col[2];
  bool val[2];
  int hoA[2], woA[2];
  const __hip_bfloat16* bsrc[2];
#pragma unroll
  for (int p = 0; p < 2; ++p) {
    col[p] = tl * 32 + p * 16 + nidx;
    val[p] = col[p] < 441;
    if (!val[p]) col[p] = 440;
    hoA[p] = col[p] / 21;
    woA[p] = col[p] - hoA[p] * 21;
    // base: img + quad's cg-pair + input row (2ho+1) + col w2=wo
    bsrc[p] = A1 + (size_t)img * IMG1E + quad * (2 * PLE) +
              ((2 * hoA[p] + 1) * 22 + woA[p]) * 8;
  }
  const __hip_bfloat16* asrc = Wf + lane * 8;

  f32x4 acc[2][4];
#pragma unroll
  for (int p = 0; p < 2; ++p)
#pragma unroll
    for (int t = 0; t < 4; ++t) acc[p][t] = (f32x4){0.f, 0.f, 0.f, 0.f};

  // offset(kk): s=kk&1, kh=(kk>>1)/3, kw=(kk>>1)%3
  //   plane part: (s*8 + ((1+kw)&1)) * PLE ; pixel part: (kh*22 + ((1+kw)>>1))*8
#define FSC_BOFF2(kk)                                                        \
  ((((kk)&1) * 8 + ((1 + (((kk) >> 1) % 3)) & 1)) * PLE +                    \
   (((((kk) >> 1)) / 3) * 22 + ((1 + (((kk) >> 1) % 3)) >> 1)) * 8)

  bf16x8 bbuf[4][2];
#pragma unroll
  for (int d = 0; d < 3; ++d)
#pragma unroll
    for (int p = 0; p < 2; ++p)
      bbuf[d][p] = *(const bf16x8*)(const void*)(bsrc[p] + FSC_BOFF2(d));

#pragma unroll
  for (int kk = 0; kk < 18; ++kk) {
    if (kk + 3 < 18) {
#pragma unroll
      for (int p = 0; p < 2; ++p)
        bbuf[(kk + 3) & 3][p] =
            *(const bf16x8*)(const void*)(bsrc[p] + FSC_BOFF2(kk + 3));
    }
#pragma unroll
    for (int t = 0; t < 4; ++t) {
      bf16x8 a = *(const bf16x8*)(const void*)(asrc + (kk * 4 + t) * 512);
#pragma unroll
      for (int p = 0; p < 2; ++p)
        acc[p][t] =
            __builtin_amdgcn_mfma_f32_16x16x32_bf16(a, bbuf[kk & 3][p], acc[p][t], 0, 0, 0);
    }
  }
#undef FSC_BOFF2

  const int isf32 = *flag;
#pragma unroll
  for (int p = 0; p < 2; ++p) {
#pragma unroll
    for (int t = 0; t < 4; ++t) {
      float v[4];
#pragma unroll
      for (int r = 0; r < 4; ++r) {
        const int cout = t * 16 + quad * 4 + r;
        float xv = acc[p][t][r] + load_ext(bias, cout, isf32);
        v[r] = xv > 0.f ? xv : 0.f;
      }
      if (val[p]) {
        __hip_bfloat16* o = out + (((size_t)img * 23 + (hoA[p] + 1)) * 23 +
                                   (woA[p] + 1)) * 64 + t * 16 + quad * 4;
        union { unsigned short u[4]; uint2 w; } pk;
#pragma unroll
        for (int r = 0; r < 4; ++r) pk.u[r] = __bfloat16_as_ushort(__float2bfloat16(v[r]));
        *(uint2*)(void*)o = pk.w;
      }
    }
  }
}

// ---- implicit-GEMM conv, CG*16 cols x 64 couts, depth-4 B prefetch (r12) ----
template <int HO, int PWI, int PWO, int ROFF, int CG>
__global__ void fsc_convp_k(const __hip_bfloat16* __restrict__ in,
                            const __hip_bfloat16* __restrict__ Wf,
                            const void* __restrict__ bias,
                            __hip_bfloat16* __restrict__ out, int N,
                            const int* __restrict__ flag) {
  constexpr int COLS = CG * 16;
  constexpr int TPI = (HO * HO + COLS - 1) / COLS;
  const int wid = blockIdx.x * 4 + (threadIdx.x >> 6);
  const int img = wid / TPI;
  if (img >= N) return;
  const int tl = wid - img * TPI;
  const int lane = threadIdx.x & 63;
  const int nidx = lane & 15, quad = lane >> 4;

  int col[CG];
  bool val[CG];
  int hoA[CG], woA[CG];
  const __hip_bfloat16* bsrc[CG];
#pragma unroll
  for (int p = 0; p < CG; ++p) {
    col[p] = tl * COLS + p * 16 + nidx;
    val[p] = col[p] < HO * HO;
    if (!val[p]) col[p] = HO * HO - 1;
    hoA[p] = col[p] / HO;
    woA[p] = col[p] - hoA[p] * HO;
    bsrc[p] = in + (((size_t)img * PWI + (2 * hoA[p] + ROFF)) * PWI +
                    (2 * woA[p] + ROFF)) * 64 + quad * 8;
  }
  const __hip_bfloat16* asrc = Wf + lane * 8;

  f32x4 acc[CG][4];
#pragma unroll
  for (int p = 0; p < CG; ++p)
#pragma unroll
    for (int t = 0; t < 4; ++t) acc[p][t] = (f32x4){0.f, 0.f, 0.f, 0.f};

#define FSC_BOFF(kk) ((((kk) >> 1) / 3 * PWI + ((kk) >> 1) % 3) * 64 + ((kk)&1) * 32)

  bf16x8 bbuf[4][CG];
#pragma unroll
  for (int d = 0; d < 3; ++d)
#pragma unroll
    for (int p = 0; p < CG; ++p)
      bbuf[d][p] = *(const bf16x8*)(const void*)(bsrc[p] + FSC_BOFF(d));

#pragma unroll
  for (int kk = 0; kk < 18; ++kk) {
    if (kk + 3 < 18) {
#pragma unroll
      for (int p = 0; p < CG; ++p)
        bbuf[(kk + 3) & 3][p] =
            *(const bf16x8*)(const void*)(bsrc[p] + FSC_BOFF(kk + 3));
    }
#pragma unroll
    for (int t = 0; t < 4; ++t) {
      bf16x8 a = *(const bf16x8*)(const void*)(asrc + (kk * 4 + t) * 512);
#pragma unroll
      for (int p = 0; p < CG; ++p)
        acc[p][t] =
            __builtin_amdgcn_mfma_f32_16x16x32_bf16(a, bbuf[kk & 3][p], acc[p][t], 0, 0, 0);
    }
  }
#undef FSC_BOFF

  const int isf32 = *flag;
#pragma unroll
  for (int p = 0; p < CG; ++p) {
#pragma unroll
    for (int t = 0; t < 4; ++t) {
      float v[4];
#pragma unroll
      for (int r = 0; r < 4; ++r) {
        const int cout = t * 16 + quad * 4 + r;
        float xv = acc[p][t][r] + load_ext(bias, cout, isf32);
        v[r] = xv > 0.f ? xv : 0.f;
      }
      if (val[p]) {
        __hip_bfloat16* o = out + (((size_t)img * PWO + (hoA[p] + 1)) * PWO +
                                   (woA[p] + 1)) * 64 + t * 16 + quad * 4;
        union { unsigned short u[4]; uint2 w; } pk;
#pragma unroll
        for (int r = 0; r < 4; ++r) pk.u[r] = __bfloat16_as_ushort(__float2bfloat16(v[r]));
        *(uint2*)(void*)o = pk.w;
      }
    }
  }
}

// ---- 32-col MFMA conv, EMB output (conv4; proven r6-r12) ----
__global__ void fsc_conv4_k(const __hip_bfloat16* __restrict__ in,
                            const __hip_bfloat16* __restrict__ Wf,
                            const void* __restrict__ bias, float* __restrict__ emb,
                            int N, const int* __restrict__ flag) {
  constexpr int HO = 6, PWI = 13;
  constexpr int TPI = 2;  // ceil(36/32)
  const int wid = blockIdx.x * 4 + (threadIdx.x >> 6);
  const int img = wid / TPI;
  if (img >= N) return;
  const int tl = wid - img * TPI;
  const int lane = threadIdx.x & 63;
  const int nidx = lane & 15, quad = lane >> 4;

  int col0 = tl * 32 + nidx;
  int col1 = col0 + 16;
  const bool val0 = col0 < HO * HO;
  const bool val1 = col1 < HO * HO;
  if (!val0) col0 = HO * HO - 1;
  if (!val1) col1 = HO * HO - 1;
  const int ho0 = col0 / HO, wo0 = col0 - ho0 * HO;
  const int ho1 = col1 / HO, wo1 = col1 - ho1 * HO;

  const __hip_bfloat16* bsrc0 =
      in + (((size_t)img * PWI + 2 * ho0) * PWI + 2 * wo0) * 64 + quad * 8;
  const __hip_bfloat16* bsrc1 =
      in + (((size_t)img * PWI + 2 * ho1) * PWI + 2 * wo1) * 64 + quad * 8;
  const __hip_bfloat16* asrc = Wf + lane * 8;

  f32x4 acc[2][4];
#pragma unroll
  for (int p = 0; p < 2; ++p)
#pragma unroll
    for (int t = 0; t < 4; ++t) acc[p][t] = (f32x4){0.f, 0.f, 0.f, 0.f};

#pragma unroll
  for (int kk = 0; kk < 18; ++kk) {
    const int s = kk & 1;
    const int khw = kk >> 1;
    const int kh = khw / 3, kw = khw - kh * 3;
    const int boff = (kh * PWI + kw) * 64 + s * 32;
    bf16x8 b0 = *(const bf16x8*)(const void*)(bsrc0 + boff);
    bf16x8 b1 = *(const bf16x8*)(const void*)(bsrc1 + boff);
#pragma unroll
    for (int t = 0; t < 4; ++t) {
      bf16x8 a = *(const bf16x8*)(const void*)(asrc + (kk * 4 + t) * 512);
      acc[0][t] = __builtin_amdgcn_mfma_f32_16x16x32_bf16(a, b0, acc[0][t], 0, 0, 0);
      acc[1][t] = __builtin_amdgcn_mfma_f32_16x16x32_bf16(a, b1, acc[1][t], 0, 0, 0);
    }
  }

  const int isf32 = *flag;
#pragma unroll
  for (int p = 0; p < 2; ++p) {
    const bool valid = p == 0 ? val0 : val1;
    const int col = p == 0 ? col0 : col1;
#pragma unroll
    for (int t = 0; t < 4; ++t) {
      float v[4];
#pragma unroll
      for (int r = 0; r < 4; ++r) {
        const int cout = t * 16 + quad * 4 + r;
        float xv = acc[p][t][r] + load_ext(bias, cout, isf32);
        v[r] = xv > 0.f ? xv : 0.f;
      }
      if (valid) {
        float* o = emb + ((size_t)img * 36 + col) * 64 + t * 16 + quad * 4;
        *(f32x4*)(void*)o = (f32x4){v[0], v[1], v[2], v[3]};
      }
    }
  }
}

// ---- head (proven r3-r12) ----
__global__ void fsc_proto_k(const float* __restrict__ emb_s, const int* __restrict__ y,
                            float* __restrict__ protos) {
  int i = blockIdx.x * blockDim.x + threadIdx.x;
  if (i >= BB * CC * DD) return;
  int d = i % DD;
  int bc = i / DD;
  int c = bc % CC;
  int b = bc / CC;
  float sum = 0.f;
  for (int s = 0; s < SS; ++s) {
    if (y[b * SS + s] % CC == c) sum += emb_s[(size_t)(b * SS + s) * DD + d];
  }
  protos[i] = sum * 0.2f;
}

__global__ void fsc_pnorm_k(const float* __restrict__ protos, float* __restrict__ pn) {
  __shared__ float red[4];
  __shared__ float inv;
  const int bc = blockIdx.x;
  const float* p = protos + (size_t)bc * DD;
  float ss = 0.f;
  for (int d = threadIdx.x; d < DD; d += 256) { float v = p[d]; ss += v * v; }
#pragma unroll
  for (int off = 32; off > 0; off >>= 1) ss += __shfl_down(ss, off);
  if ((threadIdx.x & 63) == 0) red[threadIdx.x >> 6] = ss;
  __syncthreads();
  if (threadIdx.x == 0) {
    float nrm = sqrtf(red[0] + red[1] + red[2] + red[3]);
    nrm = nrm > EPSF ? nrm : EPSF;
    inv = 1.f / nrm;
  }
  __syncthreads();
  float sc = inv;
  for (int d = threadIdx.x; d < DD; d += 256) pn[(size_t)bc * DD + d] = p[d] * sc;
}

__global__ void fsc_preds_k(const float* __restrict__ emb_t, const float* __restrict__ pn,
                            void* __restrict__ out, const int* __restrict__ flag) {
  __shared__ float red[4][6];
  __shared__ float fin[6];
  const int isf32 = *flag;
  const int bt = blockIdx.x;
  const int b = bt / TT;
  const float* et = emb_t + (size_t)bt * DD;
  float e[9];
#pragma unroll
  for (int k = 0; k < 9; ++k) e[k] = et[threadIdx.x + 256 * k];
  float vals[6];
  {
    float ss = 0.f;
#pragma unroll
    for (int k = 0; k < 9; ++k) ss += e[k] * e[k];
    vals[0] = ss;
  }
  const float* pb = pn + (size_t)b * CC * DD;
#pragma unroll
  for (int c = 0; c < CC; ++c) {
    float s = 0.f;
#pragma unroll
    for (int k = 0; k < 9; ++k) s += e[k] * pb[(size_t)c * DD + threadIdx.x + 256 * k];
    vals[1 + c] = s;
  }
#pragma unroll
  for (int v = 0; v < 6; ++v) {
#pragma unroll
    for (int off = 32; off > 0; off >>= 1) vals[v] += __shfl_down(vals[v], off);
  }
  if ((threadIdx.x & 63) == 0) {
#pragma unroll
    for (int v = 0; v < 6; ++v) red[threadIdx.x >> 6][v] = vals[v];
  }
  __syncthreads();
  if (threadIdx.x < 6)
    fin[threadIdx.x] = red[0][threadIdx.x] + red[1][threadIdx.x] +
                       red[2][threadIdx.x] + red[3][threadIdx.x];
  __syncthreads();
  if (threadIdx.x < CC) {
    float nt = sqrtf(fin[0]);
    nt = nt > EPSF ? nt : EPSF;
    float r = fin[1 + threadIdx.x] / nt;
    if (isf32) ((float*)out)[(size_t)bt * CC + threadIdx.x] = r;
    else ((__hip_bfloat16*)out)[(size_t)bt * CC + threadIdx.x] = __float2bfloat16(r);
  }
}

static inline int fsc_cdiv(int a, int b) { return (a + b - 1) / b; }
static inline int imin(int a, int b) { return a < b ? a : b; }
static inline int imax(int a, int b) { return a > b ? a : b; }

extern "C" void kernel_launch(void* const* d_in, const int* in_sizes, int n_in,
                              void* d_out, int out_size, void* d_ws, size_t ws_size,
                              hipStream_t stream) {
  const void* xs = d_in[0];
  const void* xt = d_in[1];
  const int* y = (const int*)d_in[2];
  const void* W1 = d_in[3];
  const void* b1 = d_in[4];
  const void* W2 = d_in[5];
  const void* b2 = d_in[6];
  const void* W3 = d_in[7];
  const void* b3 = d_in[8];
  const void* W4 = d_in[9];
  const void* b4 = d_in[10];

  // ---- workspace layout: fixed ~25.6 MB + X/A1/A2 chunk buffers ----
  char* w = (char*)d_ws;
  int* flag = (int*)w;                      w += 256;
  __hip_bfloat16* Wf1 = (__hip_bfloat16*)w; w += 4096 * 2;
  __hip_bfloat16* Wf2 = (__hip_bfloat16*)w; w += 36864 * 2;
  __hip_bfloat16* Wf3 = (__hip_bfloat16*)w; w += 36864 * 2;
  __hip_bfloat16* Wf4 = (__hip_bfloat16*)w; w += 36864 * 2;
  float* protos = (float*)w;                w += (size_t)BB * CC * DD * 4;
  float* pn = (float*)w;                    w += (size_t)BB * CC * DD * 4;
  float* emb = (float*)w;                   w += (size_t)NTOT * DD * 4;           // 7.37 MB
  __hip_bfloat16* C3 = (__hip_bfloat16*)w;  w += (size_t)NTOT * 13 * 13 * 64 * 2; // 17.3 MB
  char* chunk0 = w;
  const size_t fixedB = (size_t)(w - (char*)d_ws);
  const size_t szX  = (size_t)86 * 86 * 4 * 2;    //  59,168 B/img
  const size_t szA1 = (size_t)IMG1E * 2;          // 247,808 B/img (plane layout)
  const size_t szA2 = (size_t)23 * 23 * 64 * 2;   //  67,712 B/img
  const size_t perImgB = szX + szA1 + szA2;        // 374,688 B/img

  int CH = 50;
  const int cands[7] = {640, 600, 512, 400, 200, 100, 50};
  for (int k = 0; k < 7; ++k) {
    if (fixedB + (size_t)cands[k] * perImgB <= ws_size) { CH = cands[k]; break; }
  }
  __hip_bfloat16* X  = (__hip_bfloat16*)chunk0;
  __hip_bfloat16* A1 = (__hip_bfloat16*)(chunk0 + (size_t)CH * szX);
  __hip_bfloat16* A2 = (__hip_bfloat16*)(chunk0 + (size_t)CH * (szX + szA1));

  // 1. dtype probe + weight repacks
  fsc_probe_dtype_k<<<1, 256, 0, stream>>>((const unsigned short*)W2, 64 * 64 * 9, flag);
  fsc_repack_w1m_k<<<fsc_cdiv(4096, 256), 256, 0, stream>>>(W1, Wf1, flag);
  fsc_repack_wm_k<<<fsc_cdiv(36864, 256), 256, 0, stream>>>(W2, Wf2, flag);
  fsc_repack_wm_k<<<fsc_cdiv(36864, 256), 256, 0, stream>>>(W3, Wf3, flag);
  fsc_repack_wm_k<<<fsc_cdiv(36864, 256), 256, 0, stream>>>(W4, Wf4, flag);

  // 2. zero pad cells (interiors rewritten each chunk; pads stay 0)
  fsc_zero_xb_k<<<fsc_cdiv(CH * 1360, 256), 256, 0, stream>>>(X, CH);
  fsc_zero_a1p_k<<<fsc_cdiv(CH * 16 * 86 * 8, 256), 256, 0, stream>>>(A1, CH);
  fsc_zero_border_k<23><<<fsc_cdiv(CH * (4 * 23 - 4) * 64, 256), 256, 0, stream>>>(A2, CH);
  fsc_zero_border_k<13><<<fsc_cdiv(NTOT * (4 * 13 - 4) * 64, 256), 256, 0, stream>>>(C3, NTOT);

  // 3. chunks over GLOBAL image index (support 0..199, target 200..799)
  for (int g0 = 0; g0 < NTOT; g0 += CH) {
    const int n = imin(CH, NTOT - g0);
    if (g0 < NSUP) {
      const int cnt = imin(g0 + n, NSUP) - g0;
      fsc_xform1_k<<<fsc_cdiv(cnt * 7056, 256), 256, 0, stream>>>(
          xs, g0, X, 0, cnt, flag);
    }
    if (g0 + n > NSUP) {
      const int tStart = imax(g0, NSUP);
      const int cnt = g0 + n - tStart;
      fsc_xform1_k<<<fsc_cdiv(cnt * 7056, 256), 256, 0, stream>>>(
          xt, tStart - NSUP, X, tStart - g0, cnt, flag);
    }
    // conv1: NHWC4 -> A1 planes; TPI=28
    fsc_conv1m_k<<<fsc_cdiv(n * 28, 4), 256, 0, stream>>>(X, Wf1, b1, A1, n, flag);
    // conv2: A1 planes -> 21x21 into 23-pad NHWC; 32 cols (TPI=14)
    fsc_conv2p_k<<<fsc_cdiv(n * 14, 4), 256, 0, stream>>>(A1, Wf2, b2, A2, n, flag);
    // conv3: 23-pad -> 11x11 into 13-pad; ROFF=0; 16 cols (TPI=8)
    fsc_convp_k<11, 23, 13, 0, 1><<<fsc_cdiv(n * 8, 4), 256, 0, stream>>>(
        A2, Wf3, b3, C3 + (size_t)g0 * 13 * 13 * 64, n, flag);
  }

  // 4. conv4 full batch: 13-pad -> fp32 emb [800][2304]
  fsc_conv4_k<<<fsc_cdiv(NTOT * 2, 4), 256, 0, stream>>>(C3, Wf4, b4, emb, NTOT, flag);

  // 5. head
  fsc_proto_k<<<fsc_cdiv(BB * CC * DD, 256), 256, 0, stream>>>(emb, y, protos);
  fsc_pnorm_k<<<BB * CC, 256, 0, stream>>>(protos, pn);
  fsc_preds_k<<<NTGT, 256, 0, stream>>>(emb + (size_t)NSUP * DD, pn, d_out, flag);
}